// Round 10
// baseline (4745.457 us; speedup 1.0000x reference)
//
#include <hip/hip_runtime.h>
#include <math.h>

#define TT 512
#define BB 64
#define DIN 256
#define HH 512
#define DOUT 256

// Shared A tiles (hi/lo): 16 rows x 768 f16. Rows 0-7 = group A batches,
// rows 8-15 = group B batches. Cols 0-511 = h, 512-767 = x.
#define RSU 388          // row stride in u32 (384 data + 4 pad)
#define RSH 776          // row stride in f16
#define PST 68           // p_l row stride in f32

// LDS layout (u32 units)
#define A_HI_OFF 0
#define A_LO_OFF 6208    // 16*388
#define P_OFF    12416   // 32 rows x PST = 2176 (rows = kh*16 + drow)
#define B_OFF    14592   // 64 biases (gate*16 + unit)
#define C_OFF    14656   // 256 cell states (A: 0-127, B: 128-255)
#define SMEM_U32 14912
#define SMEM_BYTES (SMEM_U32*4)

#define FCS 516          // fc LDS stride

typedef _Float16 f16x8 __attribute__((ext_vector_type(8)));
typedef float    f32x4 __attribute__((ext_vector_type(4)));
typedef unsigned u32x4 __attribute__((ext_vector_type(4)));

union H16 { _Float16 f; unsigned short u; };
__device__ __forceinline__ unsigned short f16bits(_Float16 h) { H16 t; t.f = h; return t.u; }

// split x,y into f16 hi + scaled-lo (lo = (x-hi)*2048 stays in f16 normal range)
__device__ __forceinline__ void pack2(float x, float y, unsigned& hi, unsigned& lo) {
    _Float16 hx = (_Float16)x, hy = (_Float16)y;
    _Float16 lx = (_Float16)((x - (float)hx) * 2048.0f);
    _Float16 ly = (_Float16)((y - (float)hy) * 2048.0f);
    hi = (unsigned)f16bits(hx) | ((unsigned)f16bits(hy) << 16);
    lo = (unsigned)f16bits(lx) | ((unsigned)f16bits(ly) << 16);
}

// coherent (LLC) 16B load/store — the ONLY exchange path (sc0-only proven
// unsafe in R3-R5: stale L1/L2 hits tag-false-match at period 4).
__device__ __forceinline__ u32x4 ld16_cohere(const void* p) {
    u32x4 v;
    asm volatile("global_load_dwordx4 %0, %1, off sc0 sc1"
                 : "=&v"(v) : "v"(p) : "memory");
    return v;
}
__device__ __forceinline__ void st16_cohere(void* p, u32x4 v) {
    asm volatile("global_store_dwordx4 %0, %1, off sc0 sc1"
                 :: "v"(p), "v"(v) : "memory");
}

// tag check: every u16 LSB of the 16B vector must equal `par`.
__device__ __forceinline__ bool tag_ok(u32x4 v, unsigned par) {
    unsigned a = v[0] & v[1] & v[2] & v[3];
    unsigned o = v[0] | v[1] | v[2] | v[3];
    unsigned x = par ? ~a : o;
    return (x & 0x00010001u) == 0u;
}

// ---------------- W fragments: fp32 global -> f16 hi/lo REGISTERS ----------------
// Wave (ct,kh): gate ct (16 cols), 12 slices: jj<8 -> h-slice kh*8+jj,
// jj>=8 -> x-slice kh*4+(jj-8). Lane (m,q): col = ct*16+m. 96 VGPR.
__device__ __forceinline__ void load_w_regs(const float* __restrict__ Whh,
                                            const float* __restrict__ Wih,
                                            int u0, int ct, int kh, int m, int q,
                                            f16x8 (&whi)[12], f16x8 (&wlo)[12]) {
    const int C = ct*HH + u0 + m;
    const float* rowH = Whh + (size_t)C*HH;
    const float* rowI = Wih + (size_t)C*DIN;
    #pragma unroll
    for (int jj = 0; jj < 12; ++jj) {
        const int ks = (jj < 8) ? (kh*8 + jj) : (16 + kh*4 + (jj - 8));
        const float* src = (ks < 16) ? (rowH + ks*32 + q*8)
                                     : (rowI + (ks - 16)*32 + q*8);
        float4 a = ((const float4*)src)[0];
        float4 b = ((const float4*)src)[1];
        f16x8 h8, l8; _Float16 t16;
        t16=(_Float16)a.x; h8[0]=t16; l8[0]=(_Float16)((a.x-(float)t16)*2048.0f);
        t16=(_Float16)a.y; h8[1]=t16; l8[1]=(_Float16)((a.y-(float)t16)*2048.0f);
        t16=(_Float16)a.z; h8[2]=t16; l8[2]=(_Float16)((a.z-(float)t16)*2048.0f);
        t16=(_Float16)a.w; h8[3]=t16; l8[3]=(_Float16)((a.w-(float)t16)*2048.0f);
        t16=(_Float16)b.x; h8[4]=t16; l8[4]=(_Float16)((b.x-(float)t16)*2048.0f);
        t16=(_Float16)b.y; h8[5]=t16; l8[5]=(_Float16)((b.y-(float)t16)*2048.0f);
        t16=(_Float16)b.z; h8[6]=t16; l8[6]=(_Float16)((b.z-(float)t16)*2048.0f);
        t16=(_Float16)b.w; h8[7]=t16; l8[7]=(_Float16)((b.w-(float)t16)*2048.0f);
        whi[jj] = h8; wlo[jj] = l8;
    }
}

// ---------------- x staging: 8 rows (one group) into tile rows row0..row0+8 ----------------
// 256 threads (t = 0..255), src = batch-major fp32 [8][DIN or DOUT stride DIN-sized rows]
__device__ __forceinline__ void stage_x8(unsigned* __restrict__ sm32,
                                         const float* __restrict__ src,
                                         int row0, int t, int srcstride) {
    for (int r = 0; r < 2; ++r) {
        int idx4 = t + 256*r;            // 512 float4 = 8 rows x 64
        int b = idx4 >> 6, j4 = idx4 & 63;
        float4 v = ((const float4*)(src + (size_t)b*srcstride))[j4];
        unsigned h0, l0, h1, l1;
        pack2(v.x, v.y, h0, l0);
        pack2(v.z, v.w, h1, l1);
        int o = (row0 + b)*RSU + 256 + 2*j4;
        sm32[A_HI_OFF + o]     = h0;
        sm32[A_HI_OFF + o + 1] = h1;
        sm32[A_LO_OFF + o]     = l0;
        sm32[A_LO_OFF + o + 1] = l1;
    }
}
__device__ __forceinline__ void stage_x8_zero(unsigned* __restrict__ sm32,
                                              int row0, int t) {
    for (int r = 0; r < 2; ++r) {
        int idx = t + 256*r;             // 512: 8 rows x 64
        int b = idx >> 6, j = idx & 63;
        int o = (row0 + b)*RSU + 256 + 2*j;
        sm32[A_HI_OFF + o]     = 0u;
        sm32[A_HI_OFF + o + 1] = 0u;
        sm32[A_LO_OFF + o]     = 0u;
        sm32[A_LO_OFF + o + 1] = 0u;
    }
}

// ---------------- gather one group's h into tile rows row0..row0+8 ----------------
// 512 threads: thread t covers batch t>>6, units (t&63)*8..+8 (one 16B vec per buf).
__device__ __forceinline__ void gather8(unsigned* __restrict__ sm32,
                                        const unsigned short* __restrict__ hbh,
                                        const unsigned short* __restrict__ hbl,
                                        int slot, unsigned par, int gbase,
                                        int row0, int tid) {
    const unsigned short* SH = hbh + (size_t)slot*BB*HH + (size_t)gbase*HH;
    const unsigned short* SL = hbl + (size_t)slot*BB*HH + (size_t)gbase*HH;
    const int b = tid >> 6, j = tid & 63;
    const void* ph = SH + (size_t)b*HH + j*8;
    const void* pl = SL + (size_t)b*HH + j*8;
    u32x4 vh = {0,0,0,0}, vl = {0,0,0,0};
    unsigned pend = 3u;
    do {
        if (pend & 1u) vh = ld16_cohere(ph);
        if (pend & 2u) vl = ld16_cohere(pl);
        asm volatile("s_waitcnt vmcnt(0)" : "+v"(vh), "+v"(vl) :: "memory");
        if (tag_ok(vh, par)) pend &= ~1u;
        if (tag_ok(vl, par)) pend &= ~2u;
    } while (pend);
    *(u32x4*)(sm32 + A_HI_OFF + (row0 + b)*RSU + j*4) = vh;
    *(u32x4*)(sm32 + A_LO_OFF + (row0 + b)*RSU + j*4) = vl;
}

// ---------------- persistent LSTM kernel (dual phase-shifted groups per block) ----------------
// 8 batch-groups of 8; block pair p = blockIdx&3 serves gA=2p (tile rows 0-7)
// and gB=2p+1 (rows 8-15) with units u0 = (blockIdx>>2)*16. The two groups'
// recurrences are INDEPENDENT; their exchanges are phase-shifted half an
// iteration so each publish->gather gap is filled with the other group's
// gather+MFMA+EW — hiding the LLC visibility latency that R1-R9 measured as
// the step floor. Both MFMA phases use the full 16-row tile (off-phase rows
// discarded — matrix pipe is ~6% busy, the waste is free).
// Exchange protocol byte-identical to R6/R7: tag-in-data (LSB of every u16 =
// ((s+1)>>1)&1), slot=(s+1)&1, sc0sc1 publish + poll, same init.
__global__ __launch_bounds__(512, 1)
void lstm_persist(const float* __restrict__ x, const float* __restrict__ target,
                  const float* __restrict__ h0, const float* __restrict__ c0,
                  const float* __restrict__ eWih, const float* __restrict__ eWhh,
                  const float* __restrict__ eb,
                  const float* __restrict__ dWih, const float* __restrict__ dWhh,
                  const float* __restrict__ db,
                  float* __restrict__ hs,
                  unsigned short* __restrict__ hbh,   // [2][64][512] f16-hi
                  unsigned short* __restrict__ hbl)   // [2][64][512] f16-lo
{
    extern __shared__ unsigned sm32[];
    float* p_l = (float*)(sm32 + P_OFF);
    float* b_l = (float*)(sm32 + B_OFF);
    float* c_l = (float*)(sm32 + C_OFF);

    const int tid   = (int)threadIdx.x;
    const int pair  = (int)(blockIdx.x & 3);
    const int ij    = (int)(blockIdx.x >> 2);
    const int baseA = pair * 16;           // gA batches
    const int baseB = baseA + 8;           // gB batches
    const int u0    = ij * 16;

    // ---- initial staging ----
    if (tid < 256) {
        int loc = tid & 127, b = loc >> 4, u = loc & 15;
        int batch = (tid < 128 ? baseA : baseB) + b;
        c_l[tid] = c0[(size_t)batch*HH + u0 + u];
    }
    if (tid < 64) b_l[tid] = eb[(tid >> 4)*HH + u0 + (tid & 15)];
    // h_{-1} = h0 -> rows 0-7 (A), 8-15 (B)
    for (int r = 0; r < 4; ++r) {
        int idx4 = tid + 512*r;            // 2048 float4 = 16 rows x 128
        int row = idx4 >> 7, j4 = idx4 & 127;
        int batch = (row < 8) ? (baseA + row) : (baseB + row - 8);
        float4 v = ((const float4*)(h0 + (size_t)batch*HH))[j4];
        unsigned h0p, l0p, h1p, l1p;
        pack2(v.x, v.y, h0p, l0p);
        pack2(v.z, v.w, h1p, l1p);
        int o = row*RSU + 2*j4;
        sm32[A_HI_OFF + o]     = h0p;
        sm32[A_HI_OFF + o + 1] = h1p;
        sm32[A_LO_OFF + o]     = l0p;
        sm32[A_LO_OFF + o + 1] = l1p;
    }
    // x(0) for both groups
    {
        for (int r = 0; r < 2; ++r) {
            int idx4 = tid + 512*r;        // 1024 float4 = 16 rows x 64
            int row = idx4 >> 6, j4 = idx4 & 63;
            int batch = (row < 8) ? (baseA + row) : (baseB + row - 8);
            float4 v = ((const float4*)(x + (size_t)batch*DIN))[j4];
            unsigned h0p, l0p, h1p, l1p;
            pack2(v.x, v.y, h0p, l0p);
            pack2(v.z, v.w, h1p, l1p);
            int o = row*RSU + 256 + 2*j4;
            sm32[A_HI_OFF + o]     = h0p;
            sm32[A_HI_OFF + o + 1] = h1p;
            sm32[A_LO_OFF + o]     = l0p;
            sm32[A_LO_OFF + o + 1] = l1p;
        }
    }
    __syncthreads();

    const int lane = tid & 63;
    const int wid  = tid >> 6;         // 0..7
    const int m    = lane & 15;
    const int q    = lane >> 4;
    const int ct   = wid & 3;          // gate
    const int kh   = wid >> 2;         // k-half

    const _Float16* aH = (const _Float16*)(sm32 + A_HI_OFF);
    const _Float16* aL = (const _Float16*)(sm32 + A_LO_OFF);
    const int abase = m*RSH + q*8;

    f16x8 whi[12], wlo[12];
    load_w_regs(eWhh, eWih, u0, ct, kh, m, q, whi, wlo);

    const float sc = 1.0f/2048.0f;

    for (int s = 0; s < 1024; ++s) {
        const int slotG = s & 1;                         // slot holding h(s-1)
        const unsigned parG = (unsigned)((s >> 1) & 1);
        const int slotP = (s & 1) ^ 1;                   // slot for h(s)
        const unsigned parP = (unsigned)(((s + 1) >> 1) & 1);

        // ---- P1: gather h_A(s-1) -> rows 0-7 ----
        if (s > 0) gather8(sm32, hbh, hbl, slotG, parG, baseA, 0, tid);
        __syncthreads();

        // ---- P2: MFMA #1 -> gates_A(s) in p_l rows 0-7 (per kh half) ----
        {
            f32x4 hh = {0.f,0.f,0.f,0.f}, lo = {0.f,0.f,0.f,0.f};
            #pragma unroll
            for (int jj = 0; jj < 12; ++jj) {
                const int ks = (jj < 8) ? (kh*8 + jj) : (16 + kh*4 + (jj - 8));
                f16x8 ah = *(const f16x8*)(aH + abase + ks*32);
                f16x8 al = *(const f16x8*)(aL + abase + ks*32);
                hh = __builtin_amdgcn_mfma_f32_16x16x32_f16(ah, whi[jj], hh, 0, 0, 0);
                lo = __builtin_amdgcn_mfma_f32_16x16x32_f16(al, whi[jj],
                     __builtin_amdgcn_mfma_f32_16x16x32_f16(ah, wlo[jj], lo, 0, 0, 0), 0, 0, 0);
            }
            float* pb = p_l + (kh*16 + q*4)*PST + ct*16 + m;
            #pragma unroll
            for (int i = 0; i < 4; ++i) pb[i*PST] = hh[i] + lo[i]*sc;
        }
        __syncthreads();

        // ---- P3: EW_A + publish_A (tid<128) | stage x_B(s) (tid>=256) ----
        if (tid < 128) {
            const int b = tid >> 4, u = tid & 15;
            const float* p0 = p_l + (size_t)b*PST;
            const float* p1 = p_l + (size_t)(16 + b)*PST;
            float gi = b_l[u]      + p0[u]      + p1[u];
            float gf = b_l[16 + u] + p0[16 + u] + p1[16 + u];
            float gg = b_l[32 + u] + p0[32 + u] + p1[32 + u];
            float go = b_l[48 + u] + p0[48 + u] + p1[48 + u];
            float ii = 1.f/(1.f + expf(-gi));
            float ff = 1.f/(1.f + expf(-gf));
            float g2 = tanhf(gg);
            float oo = 1.f/(1.f + expf(-go));
            float c  = ff*c_l[tid] + ii*g2;
            c_l[tid] = c;
            float hval = oo*tanhf(c);
            if (s >= 512)
                hs[((size_t)(s - 512)*BB + (baseA + b))*HH + (u0 + u)] = hval;
            _Float16 hh16 = (_Float16)hval;
            unsigned uh = ((unsigned)f16bits(hh16) & 0xFFFEu) | parP;
            H16 t16; t16.u = (unsigned short)uh;
            _Float16 hl16 = (_Float16)((hval - (float)t16.f) * 2048.0f);
            unsigned ul = ((unsigned)f16bits(hl16) & 0xFFFEu) | parP;
            asm volatile("s_waitcnt vmcnt(0)" ::: "memory");
            unsigned r0h = uh | (__shfl_xor(uh, 1, 64) << 16);
            unsigned r0l = ul | (__shfl_xor(ul, 1, 64) << 16);
            u32x4 vh, vl;
            vh[0] = r0h; vh[1] = __shfl_xor(r0h, 2, 64);
            vh[2] = __shfl_xor(r0h, 4, 64); vh[3] = __shfl_xor(r0h, 6, 64);
            vl[0] = r0l; vl[1] = __shfl_xor(r0l, 2, 64);
            vl[2] = __shfl_xor(r0l, 4, 64); vl[3] = __shfl_xor(r0l, 6, 64);
            if ((u & 7) == 0) {
                const int h16 = u >> 3;
                size_t off = (size_t)slotP*BB*HH + (size_t)(baseA + b)*HH + u0 + h16*8;
                st16_cohere(hbh + off, vh);
                st16_cohere(hbl + off, vl);
            }
        } else if (tid >= 256) {
            // x_B(s): s<512 -> x ; s==512 -> zeros ; else target[s-513]
            int t = tid - 256;
            if (s < 512)       stage_x8(sm32, x + ((size_t)s*BB + baseB)*DIN, 8, t, DIN);
            else if (s == 512) stage_x8_zero(sm32, 8, t);
            else               stage_x8(sm32, target + ((size_t)(s - 513)*BB + baseB)*DOUT, 8, t, DOUT);
        }

        // ---- P4: gather h_B(s-1) -> rows 8-15 ----
        if (s > 0) gather8(sm32, hbh, hbl, slotG, parG, baseB, 8, tid);
        __syncthreads();

        // ---- P5: MFMA #2 -> gates_B(s) in p_l rows 8-15 ----
        {
            f32x4 hh = {0.f,0.f,0.f,0.f}, lo = {0.f,0.f,0.f,0.f};
            #pragma unroll
            for (int jj = 0; jj < 12; ++jj) {
                const int ks = (jj < 8) ? (kh*8 + jj) : (16 + kh*4 + (jj - 8));
                f16x8 ah = *(const f16x8*)(aH + abase + ks*32);
                f16x8 al = *(const f16x8*)(aL + abase + ks*32);
                hh = __builtin_amdgcn_mfma_f32_16x16x32_f16(ah, whi[jj], hh, 0, 0, 0);
                lo = __builtin_amdgcn_mfma_f32_16x16x32_f16(al, whi[jj],
                     __builtin_amdgcn_mfma_f32_16x16x32_f16(ah, wlo[jj], lo, 0, 0, 0), 0, 0, 0);
            }
            float* pb = p_l + (kh*16 + q*4)*PST + ct*16 + m;
            #pragma unroll
            for (int i = 0; i < 4; ++i) pb[i*PST] = hh[i] + lo[i]*sc;
        }
        __syncthreads();

        // ---- P6: EW_B + publish_B (tid in [128,256)) | stage x_A(s+1) (tid>=256) ----
        if (tid >= 128 && tid < 256) {
            const int t2 = tid - 128;
            const int b = t2 >> 4, u = t2 & 15;
            const float* p0 = p_l + (size_t)(8 + b)*PST;
            const float* p1 = p_l + (size_t)(24 + b)*PST;
            float gi = b_l[u]      + p0[u]      + p1[u];
            float gf = b_l[16 + u] + p0[16 + u] + p1[16 + u];
            float gg = b_l[32 + u] + p0[32 + u] + p1[32 + u];
            float go = b_l[48 + u] + p0[48 + u] + p1[48 + u];
            float ii = 1.f/(1.f + expf(-gi));
            float ff = 1.f/(1.f + expf(-gf));
            float g2 = tanhf(gg);
            float oo = 1.f/(1.f + expf(-go));
            float c  = ff*c_l[tid] + ii*g2;
            c_l[tid] = c;
            float hval = oo*tanhf(c);
            if (s >= 512)
                hs[((size_t)(s - 512)*BB + (baseB + b))*HH + (u0 + u)] = hval;
            _Float16 hh16 = (_Float16)hval;
            unsigned uh = ((unsigned)f16bits(hh16) & 0xFFFEu) | parP;
            H16 t16; t16.u = (unsigned short)uh;
            _Float16 hl16 = (_Float16)((hval - (float)t16.f) * 2048.0f);
            unsigned ul = ((unsigned)f16bits(hl16) & 0xFFFEu) | parP;
            asm volatile("s_waitcnt vmcnt(0)" ::: "memory");
            unsigned r0h = uh | (__shfl_xor(uh, 1, 64) << 16);
            unsigned r0l = ul | (__shfl_xor(ul, 1, 64) << 16);
            u32x4 vh, vl;
            vh[0] = r0h; vh[1] = __shfl_xor(r0h, 2, 64);
            vh[2] = __shfl_xor(r0h, 4, 64); vh[3] = __shfl_xor(r0h, 6, 64);
            vl[0] = r0l; vl[1] = __shfl_xor(r0l, 2, 64);
            vl[2] = __shfl_xor(r0l, 4, 64); vl[3] = __shfl_xor(r0l, 6, 64);
            if ((u & 7) == 0) {
                const int h16 = u >> 3;
                size_t off = (size_t)slotP*BB*HH + (size_t)(baseB + b)*HH + u0 + h16*8;
                st16_cohere(hbh + off, vh);
                st16_cohere(hbl + off, vl);
            }
        } else if (tid >= 256) {
            // x_A(s+1)
            int t = tid - 256, ns = s + 1;
            if (ns < 512)       stage_x8(sm32, x + ((size_t)ns*BB + baseA)*DIN, 0, t, DIN);
            else if (ns == 512) stage_x8_zero(sm32, 0, t);
            else if (ns < 1024) stage_x8(sm32, target + ((size_t)(ns - 513)*BB + baseA)*DOUT, 0, t, DOUT);
        }
        if (s == 511) {
            load_w_regs(dWhh, dWih, u0, ct, kh, m, q, whi, wlo);   // decoder W
            if (tid < 64) b_l[tid] = db[(tid >> 4)*HH + u0 + (tid & 15)];
        }
        __syncthreads();
    }
}

// ---------------- FC (logits) kernel ----------------
__global__ __launch_bounds__(256, 1)
void fc_kernel(const float* __restrict__ hs, const float* __restrict__ W,
               const float* __restrict__ bias, float* __restrict__ out)
{
    extern __shared__ float sm[];
    float* hs_l = sm;              // 16 x FCS
    float* w_l  = sm + 16*FCS;     // 32 x FCS

    const int tid = (int)threadIdx.x;
    const int rb = (int)(blockIdx.x >> 3);
    const int cb = (int)(blockIdx.x & 7);

    for (int r = 0; r < 8; ++r) {
        int id = tid + 256*r;
        int b = id >> 7, j = id & 127;
        float4 v = ((const float4*)(hs + (size_t)(rb*16 + b)*HH))[j];
        *(float4*)(hs_l + b*FCS + 4*j) = v;
    }
    for (int r = 0; r < 16; ++r) {
        int id = tid + 256*r;
        int c = id >> 7, j = id & 127;
        float4 v = ((const float4*)(W + (size_t)(cb*32 + c)*HH))[j];
        *(float4*)(w_l + c*FCS + 4*j) = v;
    }
    __syncthreads();

    const int kc = tid & 7, bt = (tid >> 3) & 3, ct = tid >> 5;
    float acc[4][4] = {};
    const float* ap = hs_l + (bt*4)*FCS + 4*kc;
    const float* wp = w_l  + (ct*4)*FCS + 4*kc;
    #pragma unroll 4
    for (int i = 0; i < 16; ++i) {
        float4 av[4], wv[4];
        #pragma unroll
        for (int q = 0; q < 4; ++q) av[q] = *(const float4*)(ap + q*FCS + 32*i);
        #pragma unroll
        for (int q = 0; q < 4; ++q) wv[q] = *(const float4*)(wp + q*FCS + 32*i);
        #pragma unroll
        for (int b2 = 0; b2 < 4; ++b2)
            #pragma unroll
            for (int c2 = 0; c2 < 4; ++c2)
                acc[b2][c2] += av[b2].x*wv[c2].x + av[b2].y*wv[c2].y
                             + av[b2].z*wv[c2].z + av[b2].w*wv[c2].w;
    }
    #pragma unroll
    for (int b2 = 0; b2 < 4; ++b2)
        #pragma unroll
        for (int c2 = 0; c2 < 4; ++c2) {
            float v = acc[b2][c2];
            v += __shfl_xor(v, 1, 64);
            v += __shfl_xor(v, 2, 64);
            v += __shfl_xor(v, 4, 64);
            acc[b2][c2] = v;
        }
    if (kc == 0) {
        #pragma unroll
        for (int b2 = 0; b2 < 4; ++b2)
            #pragma unroll
            for (int c2 = 0; c2 < 4; ++c2) {
                int row = rb*16 + bt*4 + b2;
                int col = cb*32 + ct*4 + c2;
                out[(size_t)row*DOUT + col] = acc[b2][c2] + bias[col];
            }
    }
}

// ---------------- in-place softmax over last dim (256) ----------------
__global__ __launch_bounds__(256, 1)
void softmax_kernel(float* __restrict__ out)
{
    int row  = (int)blockIdx.x * 4 + ((int)threadIdx.x >> 6);
    int lane = (int)threadIdx.x & 63;
    float4 v = ((const float4*)(out + (size_t)row*DOUT))[lane];
    float m = fmaxf(fmaxf(v.x, v.y), fmaxf(v.z, v.w));
    #pragma unroll
    for (int d = 1; d < 64; d <<= 1) m = fmaxf(m, __shfl_xor(m, d, 64));
    float ex = expf(v.x - m), ey = expf(v.y - m), ez = expf(v.z - m), ew = expf(v.w - m);
    float ssum = ex + ey + ez + ew;
    #pragma unroll
    for (int d = 1; d < 64; d <<= 1) ssum += __shfl_xor(ssum, d, 64);
    float inv = 1.f / ssum;
    float4 o = make_float4(ex*inv, ey*inv, ez*inv, ew*inv);
    ((float4*)(out + (size_t)row*DOUT))[lane] = o;
}

// ---------------- exchange-buffer tag init (ws poisoned 0xAA before every call) ----------------
// slot0 first gathered at s=2 expecting tag 1 -> init LSBs to 0.
// slot1 first gathered at s=1 expecting tag 0 -> init LSBs to 1.
// sc0sc1 stores: init state lives at the LLC, where all polls go.
__global__ void init_kernel(unsigned* __restrict__ hbh32, unsigned* __restrict__ hbl32)
{
    int i = (int)blockIdx.x * 256 + (int)threadIdx.x;    // 0..16383
    unsigned* base = (i < 8192) ? hbh32 : hbl32;
    int j = (i & 8191) * 4;                              // u32 offset 0..32764
    unsigned val = (j < 16384) ? 0u : 0x00010001u;       // slot0 : slot1
    u32x4 v = {val, val, val, val};
    st16_cohere(base + j, v);
}

// ---------------- launch ----------------
extern "C" void kernel_launch(void* const* d_in, const int* in_sizes, int n_in,
                              void* d_out, int out_size, void* d_ws, size_t ws_size,
                              hipStream_t stream) {
    (void)in_sizes; (void)n_in; (void)out_size; (void)ws_size;
    const float* x      = (const float*)d_in[0];
    const float* target = (const float*)d_in[1];
    const float* h0     = (const float*)d_in[2];
    const float* c0     = (const float*)d_in[3];
    const float* eWih   = (const float*)d_in[4];
    const float* eWhh   = (const float*)d_in[5];
    const float* eb     = (const float*)d_in[6];
    const float* dWih   = (const float*)d_in[7];
    const float* dWhh   = (const float*)d_in[8];
    const float* db     = (const float*)d_in[9];
    const float* fcW    = (const float*)d_in[10];
    const float* fcb    = (const float*)d_in[11];
    float* out = (float*)d_out;

    float* hs = (float*)d_ws + 1024;                    // [T*B*H] decoder hidden
    unsigned short* hbh = (unsigned short*)(hs + (size_t)TT*BB*HH);  // [2][64][512] hi
    unsigned short* hbl = hbh + (size_t)2*BB*HH;                     // [2][64][512] lo

    init_kernel<<<dim3(64), dim3(256), 0, stream>>>((unsigned*)hbh, (unsigned*)hbl);

    lstm_persist<<<dim3(128), dim3(512), SMEM_BYTES, stream>>>(
        x, target, h0, c0, eWih, eWhh, eb, dWih, dWhh, db, hs, hbh, hbl);

    size_t lds_fc = (size_t)(48*FCS) * sizeof(float);   // ~99 KB
    fc_kernel<<<dim3(16384), dim3(256), lds_fc, stream>>>(hs, fcW, fcb, out);

    softmax_kernel<<<dim3(8192), dim3(256), 0, stream>>>(out);
}

// Round 11
// 4060.721 us; speedup vs baseline: 1.1686x; 1.1686x over previous
//
#include <hip/hip_runtime.h>
#include <math.h>

#define TT 512
#define BB 64
#define DIN 256
#define HH 512
#define DOUT 256

// A tiles: A_HI / A_LO, each 16 rows (= batches) x 768 f16. No ballast rows.
#define RSU 388          // row stride in u32 (384 data + 4 pad, 16B-aligned rows)
#define RSH 776          // row stride in f16
#define PST 68           // p_l row stride in f32

// LDS layout (u32 units)
#define A_HI_OFF 0
#define A_LO_OFF 6208    // 16*388
#define P_OFF    12416   // 32 rows x PST = 2176  (rows = kh*16 + batch)
#define B_OFF    14592   // 64 biases (gate*16 + unit)
#define C_OFF    14656   // 256 cell states (batch*16 + unit)
#define HST_HI   14912   // 128 u32 (256 u16) h-hi stage
#define HST_LO   15040   // 128 u32 h-lo stage
#define SMEM_U32 15168
#define SMEM_BYTES (SMEM_U32*4)

#define FCS 516          // fc LDS stride

typedef _Float16 f16x8 __attribute__((ext_vector_type(8)));
typedef float    f32x4 __attribute__((ext_vector_type(4)));
typedef unsigned u32x4 __attribute__((ext_vector_type(4)));

union H16 { _Float16 f; unsigned short u; };
__device__ __forceinline__ unsigned short f16bits(_Float16 h) { H16 t; t.f = h; return t.u; }

// split x,y into f16 hi + scaled-lo (lo = (x-hi)*2048 stays in f16 normal range)
__device__ __forceinline__ void pack2(float x, float y, unsigned& hi, unsigned& lo) {
    _Float16 hx = (_Float16)x, hy = (_Float16)y;
    _Float16 lx = (_Float16)((x - (float)hx) * 2048.0f);
    _Float16 ly = (_Float16)((y - (float)hy) * 2048.0f);
    hi = (unsigned)f16bits(hx) | ((unsigned)f16bits(hy) << 16);
    lo = (unsigned)f16bits(lx) | ((unsigned)f16bits(ly) << 16);
}

// coherent (LLC) 16B load/store — the ONLY exchange path (sc0-only proven
// unsafe in R3-R5: stale L1/L2 hits tag-false-match at period 4).
__device__ __forceinline__ u32x4 ld16_cohere(const void* p) {
    u32x4 v;
    asm volatile("global_load_dwordx4 %0, %1, off sc0 sc1"
                 : "=&v"(v) : "v"(p) : "memory");
    return v;
}
__device__ __forceinline__ void st16_cohere(void* p, u32x4 v) {
    asm volatile("global_store_dwordx4 %0, %1, off sc0 sc1"
                 :: "v"(p), "v"(v) : "memory");
}

// tag check: every u16 LSB of the 16B vector must equal `par`.
__device__ __forceinline__ bool tag_ok(u32x4 v, unsigned par) {
    unsigned a = v[0] & v[1] & v[2] & v[3];
    unsigned o = v[0] | v[1] | v[2] | v[3];
    unsigned x = par ? ~a : o;
    return (x & 0x00010001u) == 0u;
}

// ---------------- W fragments: fp32 global -> f16 hi/lo REGISTERS ----------------
// Wave (ct,kh): ONE 16-col subtile (gate ct), k-slices kh*12..+12.
// Lane (m,q): B-frag col = ct*16+m -> W row C = ct*HH + u0 + m.
// 12 x (hi,lo) f16x8 = 96 VGPR (proven no-spill pressure level).
__device__ __forceinline__ void load_w_regs(const float* __restrict__ Whh,
                                            const float* __restrict__ Wih,
                                            int u0, int ct, int kh, int m, int q,
                                            f16x8 (&whi)[12], f16x8 (&wlo)[12]) {
    const int C = ct*HH + u0 + m;                  // gate-major row
    const float* rowH = Whh + (size_t)C*HH;
    const float* rowI = Wih + (size_t)C*DIN;
    #pragma unroll
    for (int j = 0; j < 12; ++j) {
        const int ks = kh*12 + j;                  // 0..23
        const float* src = (ks < 16) ? (rowH + ks*32 + q*8)
                                     : (rowI + (ks - 16)*32 + q*8);
        float4 a = ((const float4*)src)[0];
        float4 b = ((const float4*)src)[1];
        f16x8 h8, l8; _Float16 t16;
        t16=(_Float16)a.x; h8[0]=t16; l8[0]=(_Float16)((a.x-(float)t16)*2048.0f);
        t16=(_Float16)a.y; h8[1]=t16; l8[1]=(_Float16)((a.y-(float)t16)*2048.0f);
        t16=(_Float16)a.z; h8[2]=t16; l8[2]=(_Float16)((a.z-(float)t16)*2048.0f);
        t16=(_Float16)a.w; h8[3]=t16; l8[3]=(_Float16)((a.w-(float)t16)*2048.0f);
        t16=(_Float16)b.x; h8[4]=t16; l8[4]=(_Float16)((b.x-(float)t16)*2048.0f);
        t16=(_Float16)b.y; h8[5]=t16; l8[5]=(_Float16)((b.y-(float)t16)*2048.0f);
        t16=(_Float16)b.z; h8[6]=t16; l8[6]=(_Float16)((b.z-(float)t16)*2048.0f);
        t16=(_Float16)b.w; h8[7]=t16; l8[7]=(_Float16)((b.w-(float)t16)*2048.0f);
        whi[j] = h8; wlo[j] = l8;
    }
}

// ---------------- x staging: fp32 global -> A_HI/A_LO rows 0-15, k in [512,768) ----------------
__device__ __forceinline__ void stage_x_f16(unsigned* __restrict__ sm32,
                                            const float* __restrict__ src, int tid) {
    for (int r = 0; r < 2; ++r) {
        int idx4 = tid + 512*r;          // 1024 float4 = 16 rows x 64
        int b = idx4 >> 6, j4 = idx4 & 63;
        float4 v = ((const float4*)(src + (size_t)b*DIN))[j4];
        unsigned h0, l0, h1, l1;
        pack2(v.x, v.y, h0, l0);
        pack2(v.z, v.w, h1, l1);
        int o = b*RSU + 256 + 2*j4;
        sm32[A_HI_OFF + o]     = h0;
        sm32[A_HI_OFF + o + 1] = h1;
        sm32[A_LO_OFF + o]     = l0;
        sm32[A_LO_OFF + o + 1] = l1;
    }
}

__device__ __forceinline__ void stage_x_zero_f16(unsigned* __restrict__ sm32, int tid) {
    for (int r = 0; r < 2; ++r) {
        int idx = tid + 512*r;           // 1024: 16 rows x 64
        int row = idx >> 6, j = idx & 63;
        int o = row*RSU + 256 + 2*j;
        sm32[A_HI_OFF + o]     = 0u;
        sm32[A_HI_OFF + o + 1] = 0u;
        sm32[A_LO_OFF + o]     = 0u;
        sm32[A_LO_OFF + o + 1] = 0u;
    }
}

// ---------------- persistent LSTM kernel (R7 structure + paced polling) ----------------
// Geometry: 4 batch-groups (g = blockIdx&3) x 16 batches; 32 producers/group
// (ij = blockIdx>>2) x 16 h-units. 128 blocks x 512 threads (2 waves/SIMD).
// Exchange protocol (proven): tag-in-data (LSB of every u16 = ((s+1)>>1)&1),
// slot=(s+1)&1, sc0sc1 publish + poll. Poll pacing (new vs R7): after the
// first missed round, s_sleep between retries — 128 blocks x 8 waves hammer
// the same 64KB of LLC lines; pacing cuts fabric contention on the RTT.
__global__ __launch_bounds__(512, 1)
void lstm_persist(const float* __restrict__ x, const float* __restrict__ target,
                  const float* __restrict__ h0, const float* __restrict__ c0,
                  const float* __restrict__ eWih, const float* __restrict__ eWhh,
                  const float* __restrict__ eb,
                  const float* __restrict__ dWih, const float* __restrict__ dWhh,
                  const float* __restrict__ db,
                  float* __restrict__ hs,
                  unsigned short* __restrict__ hbh,   // [2][64][512] f16-hi
                  unsigned short* __restrict__ hbl)   // [2][64][512] f16-lo
{
    extern __shared__ unsigned sm32[];
    float* p_l = (float*)(sm32 + P_OFF);
    float* b_l = (float*)(sm32 + B_OFF);
    float* c_l = (float*)(sm32 + C_OFF);
    unsigned* hst_hi = sm32 + HST_HI;
    unsigned* hst_lo = sm32 + HST_LO;

    const int tid = (int)threadIdx.x;
    const int g   = (int)(blockIdx.x & 3);     // batch group 0..3
    const int ij  = (int)(blockIdx.x >> 2);    // producer id 0..31
    const int b0  = g * 16;
    const int u0  = ij * 16;

    // ---- initial staging ----
    if (tid < 256) {
        int b = tid >> 4, u = tid & 15;
        c_l[tid] = c0[(size_t)(b0 + b)*HH + u0 + u];
    }
    if (tid < 64) b_l[tid] = eb[(tid >> 4)*HH + u0 + (tid & 15)];
    stage_x_f16(sm32, x + (size_t)b0*DIN, tid);     // x for s=0
    for (int r = 0; r < 4; ++r) {                    // h_{-1}=h0 -> A rows 0-15
        int idx4 = tid + 512*r;          // 2048 float4 = 16 rows x 128
        int b = idx4 >> 7, j4 = idx4 & 127;
        float4 v = ((const float4*)(h0 + (size_t)(b0 + b)*HH))[j4];
        unsigned h0p, l0p, h1p, l1p;
        pack2(v.x, v.y, h0p, l0p);
        pack2(v.z, v.w, h1p, l1p);
        int o = b*RSU + 2*j4;
        sm32[A_HI_OFF + o]     = h0p;
        sm32[A_HI_OFF + o + 1] = h1p;
        sm32[A_LO_OFF + o]     = l0p;
        sm32[A_LO_OFF + o + 1] = l1p;
    }
    __syncthreads();

    const int lane = tid & 63;
    const int wid  = tid >> 6;         // 0..7
    const int m    = lane & 15;        // A row sel / B col sel
    const int q    = lane >> 4;        // quad
    const int ct   = wid & 3;          // gate 0..3 (16-col subtile)
    const int kh   = wid >> 2;         // k-half (12 of 24 slices)

    const _Float16* aH = (const _Float16*)(sm32 + A_HI_OFF);
    const _Float16* aL = (const _Float16*)(sm32 + A_LO_OFF);
    const int abase = m*RSH + q*8 + (kh*12)*32;

    f16x8 whi[12], wlo[12];
    load_w_regs(eWhh, eWih, u0, ct, kh, m, q, whi, wlo);

    for (int s = 0; s < 1024; ++s) {
        // ---- 1. MFMA GEMM: C[16 batches x 16 cols] per wave, 3 products ----
        f32x4 hh = {0.f,0.f,0.f,0.f}, hl = {0.f,0.f,0.f,0.f}, lh = {0.f,0.f,0.f,0.f};
        #pragma unroll
        for (int j = 0; j < 12; ++j) {
            f16x8 ah = *(const f16x8*)(aH + abase + j*32);
            f16x8 al = *(const f16x8*)(aL + abase + j*32);
            hh = __builtin_amdgcn_mfma_f32_16x16x32_f16(ah, whi[j], hh, 0, 0, 0);
            hl = __builtin_amdgcn_mfma_f32_16x16x32_f16(ah, wlo[j], hl, 0, 0, 0);
            lh = __builtin_amdgcn_mfma_f32_16x16x32_f16(al, whi[j], lh, 0, 0, 0);
        }
        {
            // D: col = lane&15 = m (gate-col), row = q*4+i (batch).
            const float sc = 1.0f/2048.0f;
            float* pb = p_l + (kh*16 + q*4)*PST + ct*16 + m;
            #pragma unroll
            for (int i = 0; i < 4; ++i)
                pb[i*PST] = hh[i] + (hl[i] + lh[i])*sc;
        }
        __syncthreads();

        const unsigned par = (unsigned)(((s + 1) >> 1) & 1);   // step tag bit

        // ---- 2. elementwise LSTM update -> LDS h-stage (tagged split-f16) ----
        float hval = 0.f;
        if (tid < 256) {
            const int b = tid >> 4, u = tid & 15;
            const float* p0 = p_l + (size_t)b*PST;          // kh=0 slab
            const float* p1 = p_l + (size_t)(16 + b)*PST;   // kh=1 slab
            float gi = b_l[u]      + p0[u]      + p1[u];
            float gf = b_l[16 + u] + p0[16 + u] + p1[16 + u];
            float gg = b_l[32 + u] + p0[32 + u] + p1[32 + u];
            float go = b_l[48 + u] + p0[48 + u] + p1[48 + u];
            float ii = 1.f/(1.f + expf(-gi));
            float ff = 1.f/(1.f + expf(-gf));
            float g2 = tanhf(gg);
            float oo = 1.f/(1.f + expf(-go));
            float c  = ff*c_l[tid] + ii*g2;
            c_l[tid] = c;
            hval = oo*tanhf(c);
            _Float16 hh16 = (_Float16)hval;
            unsigned uh = ((unsigned)f16bits(hh16) & 0xFFFEu) | par;
            H16 t16; t16.u = (unsigned short)uh;
            _Float16 hl16 = (_Float16)((hval - (float)t16.f) * 2048.0f);
            unsigned ul = ((unsigned)f16bits(hl16) & 0xFFFEu) | par;
            ((unsigned short*)hst_hi)[tid] = (unsigned short)uh;   // tid = b*16+u
            ((unsigned short*)hst_lo)[tid] = (unsigned short)ul;
        }
        __syncthreads();

        // ---- 3. publish: 64 coherent 16B stores (16 batches x 32B x hi/lo) ----
        if (tid < 64) {
            // order prior-step publishes before this one (waits on ~1-step-old
            // traffic only -> essentially free); guarantees period-4 tag safety.
            asm volatile("s_waitcnt vmcnt(0)" ::: "memory");
            const int b = tid >> 2, part = tid & 3;
            const int isLo = part >> 1, h16 = part & 1;
            u32x4 v = *(const u32x4*)((isLo ? hst_lo : hst_hi) + b*8 + h16*4);
            unsigned short* base = (isLo ? hbl : hbh)
                + ((size_t)((s & 1) ^ 1)*BB + b0 + b)*HH + u0 + h16*8;
            st16_cohere(base, v);
        }

        // ---- 4. off-critical-path tail ----
        if (s >= 512 && tid < 256) {
            int b = tid >> 4, u = tid & 15;
            hs[((size_t)(s - 512)*BB + (b0 + b))*HH + (u0 + u)] = hval;
        }
        if (s == 511) {
            load_w_regs(dWhh, dWih, u0, ct, kh, m, q, whi, wlo);   // decoder W
            if (tid < 64) b_l[tid] = db[(tid >> 4)*HH + u0 + (tid & 15)];
        }
        {
            int ns = s + 1;
            if (ns < 1024) {
                if (ns == 512)       stage_x_zero_f16(sm32, tid);
                else if (ns < 512)   stage_x_f16(sm32, x + ((size_t)ns*BB + b0)*DIN, tid);
                else                 stage_x_f16(sm32, target + ((size_t)(ns - 513)*BB + b0)*DOUT, tid);
            }
        }

        // ---- 5. gather h_s: poll the data itself (paced retries) ----
        if (s < 1023) {
            const int slot = (s + 1) & 1;
            const u32x4* SH = (const u32x4*)(hbh + (size_t)slot*BB*HH + (size_t)b0*HH);
            const u32x4* SL = (const u32x4*)(hbl + (size_t)slot*BB*HH + (size_t)b0*HH);
            u32x4 v0 = {0,0,0,0}, v1 = {0,0,0,0}, v2 = {0,0,0,0}, v3 = {0,0,0,0};
            unsigned pend = 0xFu; int tries = 0;
            do {
                if (pend & 1u) v0 = ld16_cohere(SH + tid);
                if (pend & 2u) v1 = ld16_cohere(SH + tid + 512);
                if (pend & 4u) v2 = ld16_cohere(SL + tid);
                if (pend & 8u) v3 = ld16_cohere(SL + tid + 512);
                asm volatile("s_waitcnt vmcnt(0)"
                             : "+v"(v0), "+v"(v1), "+v"(v2), "+v"(v3) :: "memory");
                if (tag_ok(v0, par)) pend &= ~1u;
                if (tag_ok(v1, par)) pend &= ~2u;
                if (tag_ok(v2, par)) pend &= ~4u;
                if (tag_ok(v3, par)) pend &= ~8u;
                ++tries;
                if (pend && tries >= 2) __builtin_amdgcn_s_sleep(1);
            } while (pend);
            // scatter: hi -> A_HI, lo -> A_LO; 16 rows x 512 units (k<512)
            const int j = tid & 63, r0 = tid >> 6;
            *(u32x4*)(sm32 + A_HI_OFF + (r0    )*RSU + j*4) = v0;
            *(u32x4*)(sm32 + A_HI_OFF + (r0 + 8)*RSU + j*4) = v1;
            *(u32x4*)(sm32 + A_LO_OFF + (r0    )*RSU + j*4) = v2;
            *(u32x4*)(sm32 + A_LO_OFF + (r0 + 8)*RSU + j*4) = v3;
        }
        __syncthreads();   // A (h+x) visible before next MFMA
    }
}

// ---------------- FC (logits) kernel ----------------
__global__ __launch_bounds__(256, 1)
void fc_kernel(const float* __restrict__ hs, const float* __restrict__ W,
               const float* __restrict__ bias, float* __restrict__ out)
{
    extern __shared__ float sm[];
    float* hs_l = sm;              // 16 x FCS
    float* w_l  = sm + 16*FCS;     // 32 x FCS

    const int tid = (int)threadIdx.x;
    const int rb = (int)(blockIdx.x >> 3);
    const int cb = (int)(blockIdx.x & 7);

    for (int r = 0; r < 8; ++r) {
        int id = tid + 256*r;
        int b = id >> 7, j = id & 127;
        float4 v = ((const float4*)(hs + (size_t)(rb*16 + b)*HH))[j];
        *(float4*)(hs_l + b*FCS + 4*j) = v;
    }
    for (int r = 0; r < 16; ++r) {
        int id = tid + 256*r;
        int c = id >> 7, j = id & 127;
        float4 v = ((const float4*)(W + (size_t)(cb*32 + c)*HH))[j];
        *(float4*)(w_l + c*FCS + 4*j) = v;
    }
    __syncthreads();

    const int kc = tid & 7, bt = (tid >> 3) & 3, ct = tid >> 5;
    float acc[4][4] = {};
    const float* ap = hs_l + (bt*4)*FCS + 4*kc;
    const float* wp = w_l  + (ct*4)*FCS + 4*kc;
    #pragma unroll 4
    for (int i = 0; i < 16; ++i) {
        float4 av[4], wv[4];
        #pragma unroll
        for (int q = 0; q < 4; ++q) av[q] = *(const float4*)(ap + q*FCS + 32*i);
        #pragma unroll
        for (int q = 0; q < 4; ++q) wv[q] = *(const float4*)(wp + q*FCS + 32*i);
        #pragma unroll
        for (int b2 = 0; b2 < 4; ++b2)
            #pragma unroll
            for (int c2 = 0; c2 < 4; ++c2)
                acc[b2][c2] += av[b2].x*wv[c2].x + av[b2].y*wv[c2].y
                             + av[b2].z*wv[c2].z + av[b2].w*wv[c2].w;
    }
    #pragma unroll
    for (int b2 = 0; b2 < 4; ++b2)
        #pragma unroll
        for (int c2 = 0; c2 < 4; ++c2) {
            float v = acc[b2][c2];
            v += __shfl_xor(v, 1, 64);
            v += __shfl_xor(v, 2, 64);
            v += __shfl_xor(v, 4, 64);
            acc[b2][c2] = v;
        }
    if (kc == 0) {
        #pragma unroll
        for (int b2 = 0; b2 < 4; ++b2)
            #pragma unroll
            for (int c2 = 0; c2 < 4; ++c2) {
                int row = rb*16 + bt*4 + b2;
                int col = cb*32 + ct*4 + c2;
                out[(size_t)row*DOUT + col] = acc[b2][c2] + bias[col];
            }
    }
}

// ---------------- in-place softmax over last dim (256) ----------------
__global__ __launch_bounds__(256, 1)
void softmax_kernel(float* __restrict__ out)
{
    int row  = (int)blockIdx.x * 4 + ((int)threadIdx.x >> 6);
    int lane = (int)threadIdx.x & 63;
    float4 v = ((const float4*)(out + (size_t)row*DOUT))[lane];
    float m = fmaxf(fmaxf(v.x, v.y), fmaxf(v.z, v.w));
    #pragma unroll
    for (int d = 1; d < 64; d <<= 1) m = fmaxf(m, __shfl_xor(m, d, 64));
    float ex = expf(v.x - m), ey = expf(v.y - m), ez = expf(v.z - m), ew = expf(v.w - m);
    float ssum = ex + ey + ez + ew;
    #pragma unroll
    for (int d = 1; d < 64; d <<= 1) ssum += __shfl_xor(ssum, d, 64);
    float inv = 1.f / ssum;
    float4 o = make_float4(ex*inv, ey*inv, ez*inv, ew*inv);
    ((float4*)(out + (size_t)row*DOUT))[lane] = o;
}

// ---------------- exchange-buffer tag init (ws poisoned 0xAA before every call) ----------------
// slot0 first read at s=1 expects tag 1 -> init LSBs to 0.
// slot1 first read at s=0 expects tag 0 -> init LSBs to 1.
// sc0sc1 stores: init state lives at the LLC, where all polls go.
__global__ void init_kernel(unsigned* __restrict__ hbh32, unsigned* __restrict__ hbl32)
{
    int i = (int)blockIdx.x * 256 + (int)threadIdx.x;    // 0..16383
    unsigned* base = (i < 8192) ? hbh32 : hbl32;
    int j = (i & 8191) * 4;                              // u32 offset 0..32764
    unsigned val = (j < 16384) ? 0u : 0x00010001u;       // slot0 : slot1
    u32x4 v = {val, val, val, val};
    st16_cohere(base + j, v);
}

// ---------------- launch ----------------
extern "C" void kernel_launch(void* const* d_in, const int* in_sizes, int n_in,
                              void* d_out, int out_size, void* d_ws, size_t ws_size,
                              hipStream_t stream) {
    (void)in_sizes; (void)n_in; (void)out_size; (void)ws_size;
    const float* x      = (const float*)d_in[0];
    const float* target = (const float*)d_in[1];
    const float* h0     = (const float*)d_in[2];
    const float* c0     = (const float*)d_in[3];
    const float* eWih   = (const float*)d_in[4];
    const float* eWhh   = (const float*)d_in[5];
    const float* eb     = (const float*)d_in[6];
    const float* dWih   = (const float*)d_in[7];
    const float* dWhh   = (const float*)d_in[8];
    const float* db     = (const float*)d_in[9];
    const float* fcW    = (const float*)d_in[10];
    const float* fcb    = (const float*)d_in[11];
    float* out = (float*)d_out;

    float* hs = (float*)d_ws + 1024;                    // [T*B*H] decoder hidden
    unsigned short* hbh = (unsigned short*)(hs + (size_t)TT*BB*HH);  // [2][64][512] hi
    unsigned short* hbl = hbh + (size_t)2*BB*HH;                     // [2][64][512] lo

    init_kernel<<<dim3(64), dim3(256), 0, stream>>>((unsigned*)hbh, (unsigned*)hbl);

    lstm_persist<<<dim3(128), dim3(512), SMEM_BYTES, stream>>>(
        x, target, h0, c0, eWih, eWhh, eb, dWih, dWhh, db, hs, hbh, hbl);

    size_t lds_fc = (size_t)(48*FCS) * sizeof(float);   // ~99 KB
    fc_kernel<<<dim3(16384), dim3(256), lds_fc, stream>>>(hs, fcW, fcb, out);

    softmax_kernel<<<dim3(8192), dim3(256), 0, stream>>>(out);
}